// Round 7
// baseline (20222.102 us; speedup 1.0000x reference)
//
#include <hip/hip_runtime.h>

#define BB 64
#define NN 1000
#define FF 12
#define EE 64
#define HH 128
#define OO 16
#define GG 512

__device__ __forceinline__ float rcp_(float x){ return __builtin_amdgcn_rcpf(x); }
// tanh(x) = 1 - 2/(e^{2x}+1)
__device__ __forceinline__ float tanh_(float x){ return 1.0f - 2.0f*rcp_(__expf(2.0f*x) + 1.0f); }

// barrier draining only LDS counters; global loads/stores stay in flight
__device__ __forceinline__ void barrier_lds_(){
    asm volatile("s_waitcnt lgkmcnt(0)" ::: "memory");
    __builtin_amdgcn_s_barrier();
    asm volatile("" ::: "memory");
}

__global__ __launch_bounds__(512, 2)
void decoder_kernel(const float* __restrict__ enc,   // (B,1,N,E)
                    const float* __restrict__ mean,  // (B,FUT,N,O)
                    const float* __restrict__ sv,    // (1,O)
                    const float* __restrict__ h0,    // (2,O)
                    const float* __restrict__ c0,    // (2,H)
                    const float* __restrict__ Wih0,  // (G, E+O)
                    const float* __restrict__ Whh0,  // (G, O)
                    const float* __restrict__ bih0,  // (G)
                    const float* __restrict__ bhh0,  // (G)
                    const float* __restrict__ Whr0,  // (O, H)
                    const float* __restrict__ Wih1,  // (G, O)
                    const float* __restrict__ Whh1,  // (G, O)
                    const float* __restrict__ bih1,  // (G)
                    const float* __restrict__ bhh1,  // (G)
                    const float* __restrict__ Whr1,  // (O, H)
                    float* __restrict__ out)         // (B,FUT,N,O)
{
    const int t = threadIdx.x;   // gate index for both layers
    const int b = blockIdx.x;    // batch chain

    __shared__ __align__(16) float s_last[OO];
    __shared__ __align__(16) float s_h1[OO];
    __shared__ __align__(16) float s_h2[OO];
    __shared__ __align__(16) float s_gates[GG];
    __shared__ __align__(16) float s_hfull[HH];
    __shared__ __align__(16) float s_enc[EE];
    __shared__ __align__(16) float s_nm[2][OO];

    // ---- per-thread recurrent weights in registers ----
    float w_loop[16], w_hh0[16], w_ih1[16], w_hh1[16], wp0[4], wp1[4];
    {
        const float4* pL = (const float4*)(Wih0 + (size_t)t*(EE+OO) + EE);
        const float4* pH = (const float4*)(Whh0 + (size_t)t*OO);
        const float4* pI = (const float4*)(Wih1 + (size_t)t*OO);
        const float4* pG = (const float4*)(Whh1 + (size_t)t*OO);
        #pragma unroll
        for (int i=0;i<4;i++){
            float4 v;
            v=pL[i]; w_loop[4*i]=v.x; w_loop[4*i+1]=v.y; w_loop[4*i+2]=v.z; w_loop[4*i+3]=v.w;
            v=pH[i]; w_hh0[4*i]=v.x; w_hh0[4*i+1]=v.y; w_hh0[4*i+2]=v.z; w_hh0[4*i+3]=v.w;
            v=pI[i]; w_ih1[4*i]=v.x; w_ih1[4*i+1]=v.y; w_ih1[4*i+2]=v.z; w_ih1[4*i+3]=v.w;
            v=pG[i]; w_hh1[4*i]=v.x; w_hh1[4*i+1]=v.y; w_hh1[4*i+2]=v.z; w_hh1[4*i+3]=v.w;
        }
    }
    const float bias0 = bih0[t] + bhh0[t];
    const float bias1 = bih1[t] + bhh1[t];
    // single-exp activation: am=1 -> sigmoid, am=2 -> tanh. gates[256:384] are 'g'.
    const float am = ((t >> 7) == 2) ? 2.0f : 1.0f;

    // projection assignment: output j16 = t>>5, k-chunk kb = (t&31)*4
    const int j16 = t >> 5;
    const int kb  = (t & 31) * 4;
    {
        float4 q0 = *(const float4*)(Whr0 + (size_t)j16*HH + kb);
        float4 q1 = *(const float4*)(Whr1 + (size_t)j16*HH + kb);
        wp0[0]=q0.x; wp0[1]=q0.y; wp0[2]=q0.z; wp0[3]=q0.w;
        wp1[0]=q1.x; wp1[1]=q1.y; wp1[2]=q1.z; wp1[3]=q1.w;
    }

    // cell state lives in threads 0..127
    float c1 = (t < HH) ? c0[t]      : 0.0f;
    float c2 = (t < HH) ? c0[HH + t] : 0.0f;

    const float* encB  = enc  + (size_t)b * NN * EE;
    const float* meanB = mean + (size_t)b * FF * NN * OO;
    float*       outB  = out  + (size_t)b * FF * NN * OO;

    // ---- prologue: states + node-0 data ----
    if (t < OO){
        s_last[t] = sv[t];        // last0 = s[0]
        s_h1[t]   = h0[t];        // h_0[0]
        s_h2[t]   = h0[OO + t];   // h_0[1]
        ((float4*)s_enc)[t] = ((const float4*)encB)[t];   // enc node 0
    } else if (t < 2*OO){
        const int j = t - OO;
        float a = 0.0f;
        #pragma unroll
        for (int ff=0; ff<FF; ++ff) a += meanB[((size_t)ff*NN)*OO + j];
        s_nm[0][j] = a * (1.0f/12.0f);
    }
    __syncthreads();

    // pre0(node 0) = bias0 + enc.Wrow + nm.w_loop  (Wih0 streamed from L2)
    float pre0;
    {
        float s = bias0;
        const float4* wp = (const float4*)(Wih0 + (size_t)t*(EE+OO));
        const float4* ep = (const float4*)s_enc;
        #pragma unroll
        for (int e=0;e<16;e++){
            float4 wv = wp[e], ev = ep[e];
            s += ev.x*wv.x + ev.y*wv.y + ev.z*wv.z + ev.w*wv.w;
        }
        const float4* nm4 = (const float4*)s_nm[0];
        #pragma unroll
        for (int i=0;i<4;i++){
            float4 m = nm4[i];
            s += m.x*w_loop[4*i] + m.y*w_loop[4*i+1] + m.z*w_loop[4*i+2] + m.w*w_loop[4*i+3];
        }
        pre0 = s;
    }

    float4 ef = make_float4(0.f,0.f,0.f,0.f);   // enc prefetch (threads 0..15)
    float nmr[12];                               // nm prefetch (threads 16..31)
    #pragma unroll
    for (int i=0;i<12;i++) nmr[i]=0.f;

    for (int n = 0; n < NN; ++n){
        for (int f = 0; f < FF; ++f){
            // ---- B1: layer-0 gates ----
            {
                float acc = pre0;
                const float4* pa = (const float4*)s_last;
                const float4* pb = (const float4*)s_h1;
                float x0=0,x1=0,x2=0,x3=0, y0=0,y1=0,y2=0,y3=0;
                #pragma unroll
                for (int i=0;i<4;i++){
                    float4 a = pa[i];
                    x0 += a.x*w_loop[4*i];   x1 += a.y*w_loop[4*i+1];
                    x2 += a.z*w_loop[4*i+2]; x3 += a.w*w_loop[4*i+3];
                    float4 c = pb[i];
                    y0 += c.x*w_hh0[4*i];   y1 += c.y*w_hh0[4*i+1];
                    y2 += c.z*w_hh0[4*i+2]; y3 += c.w*w_hh0[4*i+3];
                }
                acc += (x0+x1)+(x2+x3) + (y0+y1)+(y2+y3);
                s_gates[t] = 1.f - am * rcp_(__expf(am*acc) + 1.f);
            }
            barrier_lds_();                                   // B1

            // ---- B2: layer-0 cell (threads 0..127) ----
            if (t < HH){
                float iv = s_gates[t],      fv = s_gates[HH + t];
                float gv = s_gates[2*HH+t], ov = s_gates[3*HH + t];
                c1 = fv*c1 + iv*gv;
                s_hfull[t] = ov * tanh_(c1);
            }
            barrier_lds_();                                   // B2

            // ---- B3: layer-0 projection ----
            {
                float4 h4 = *(const float4*)&s_hfull[kb];
                float p = h4.x*wp0[0] + h4.y*wp0[1] + h4.z*wp0[2] + h4.w*wp0[3];
                p += __shfl_down(p, 16, 32);
                p += __shfl_down(p,  8, 32);
                p += __shfl_down(p,  4, 32);
                p += __shfl_down(p,  2, 32);
                p += __shfl_down(p,  1, 32);
                if ((t & 31) == 0) s_h1[j16] = p;
            }
            barrier_lds_();                                   // B3

            // ---- B4: layer-1 gates ----
            {
                float acc1 = bias1;
                const float4* pa = (const float4*)s_h1;
                const float4* pb = (const float4*)s_h2;
                float x0=0,x1=0,x2=0,x3=0, y0=0,y1=0,y2=0,y3=0;
                #pragma unroll
                for (int i=0;i<4;i++){
                    float4 a = pa[i];
                    x0 += a.x*w_ih1[4*i];   x1 += a.y*w_ih1[4*i+1];
                    x2 += a.z*w_ih1[4*i+2]; x3 += a.w*w_ih1[4*i+3];
                    float4 c = pb[i];
                    y0 += c.x*w_hh1[4*i];   y1 += c.y*w_hh1[4*i+1];
                    y2 += c.z*w_hh1[4*i+2]; y3 += c.w*w_hh1[4*i+3];
                }
                acc1 += (x0+x1)+(x2+x3) + (y0+y1)+(y2+y3);
                s_gates[t] = 1.f - am * rcp_(__expf(am*acc1) + 1.f);
            }
            // prefetch node n+1: issue loads at f==8, land in LDS at f==10.
            // (lgkm-only barriers never drain these vmem loads on-chain)
            if (f == 8 && n+1 < NN){
                if (t < OO){
                    ef = ((const float4*)(encB + (size_t)(n+1)*EE))[t];
                } else if (t < 2*OO){
                    const int j = t - OO;
                    #pragma unroll
                    for (int ff=0; ff<FF; ++ff) nmr[ff] = meanB[((size_t)ff*NN + (n+1))*OO + j];
                }
            }
            if (f == 10 && n+1 < NN){
                if (t < OO){
                    ((float4*)s_enc)[t] = ef;
                } else if (t < 2*OO){
                    float a = 0.f;
                    #pragma unroll
                    for (int ff=0; ff<FF; ++ff) a += nmr[ff];
                    s_nm[(n+1)&1][t-OO] = a * (1.0f/12.0f);
                }
            }
            barrier_lds_();                                   // B4

            // ---- B5: layer-1 cell ----
            if (t < HH){
                float iv = s_gates[t],      fv = s_gates[HH + t];
                float gv = s_gates[2*HH+t], ov = s_gates[3*HH + t];
                c2 = fv*c2 + iv*gv;
                s_hfull[t] = ov * tanh_(c2);
            }
            barrier_lds_();                                   // B5

            // ---- B6: layer-1 projection + output ----
            {
                float4 h4 = *(const float4*)&s_hfull[kb];
                float p = h4.x*wp1[0] + h4.y*wp1[1] + h4.z*wp1[2] + h4.w*wp1[3];
                p += __shfl_down(p, 16, 32);
                p += __shfl_down(p,  8, 32);
                p += __shfl_down(p,  4, 32);
                p += __shfl_down(p,  2, 32);
                p += __shfl_down(p,  1, 32);
                if ((t & 31) == 0){
                    s_h2[j16]   = p;
                    s_last[j16] = p;
                    outB[((size_t)f*NN + n)*OO + j16] = p + s_nm[n&1][j16];
                }
            }
            // recompute pre0 for node n+1 off the node-start chain (1/12 of steps;
            // s_enc / s_nm[(n+1)&1] landed at f==10, two barriers ago)
            if (f == 11 && n+1 < NN){
                float s = bias0;
                const float4* wp = (const float4*)(Wih0 + (size_t)t*(EE+OO));
                const float4* ep = (const float4*)s_enc;
                #pragma unroll
                for (int e=0;e<16;e++){
                    float4 wv = wp[e], ev = ep[e];
                    s += ev.x*wv.x + ev.y*wv.y + ev.z*wv.z + ev.w*wv.w;
                }
                const float4* nm4 = (const float4*)s_nm[(n+1)&1];
                #pragma unroll
                for (int i=0;i<4;i++){
                    float4 m = nm4[i];
                    s += m.x*w_loop[4*i] + m.y*w_loop[4*i+1] + m.z*w_loop[4*i+2] + m.w*w_loop[4*i+3];
                }
                pre0 = s;
            }
            barrier_lds_();                                   // B6
        }
    }
}

extern "C" void kernel_launch(void* const* d_in, const int* in_sizes, int n_in,
                              void* d_out, int out_size, void* d_ws, size_t ws_size,
                              hipStream_t stream) {
    const float* enc  = (const float*)d_in[0];
    const float* mean = (const float*)d_in[1];
    const float* sv   = (const float*)d_in[2];
    const float* h0   = (const float*)d_in[3];
    const float* c0   = (const float*)d_in[4];
    const float* Wih0 = (const float*)d_in[5];
    const float* Whh0 = (const float*)d_in[6];
    const float* bih0 = (const float*)d_in[7];
    const float* bhh0 = (const float*)d_in[8];
    const float* Whr0 = (const float*)d_in[9];
    const float* Wih1 = (const float*)d_in[10];
    const float* Whh1 = (const float*)d_in[11];
    const float* bih1 = (const float*)d_in[12];
    const float* bhh1 = (const float*)d_in[13];
    const float* Whr1 = (const float*)d_in[14];
    float* out = (float*)d_out;

    decoder_kernel<<<dim3(BB), dim3(512), 0, stream>>>(
        enc, mean, sv, h0, c0,
        Wih0, Whh0, bih0, bhh0, Whr0,
        Wih1, Whh1, bih1, bhh1, Whr1,
        out);
}

// Round 8
// 16040.239 us; speedup vs baseline: 1.2607x; 1.2607x over previous
//
#include <hip/hip_runtime.h>

#define BB 64
#define NN 1000
#define FF 12
#define EE 64
#define HH 128
#define OO 16
#define GG 512

__device__ __forceinline__ float rcp_(float x){ return __builtin_amdgcn_rcpf(x); }
__device__ __forceinline__ float sigm_(float x){ return rcp_(1.0f + __expf(-x)); }
// exact algebraic form of tanh: (e^{2x}-1)/(e^{2x}+1) = 1 - 2/(e^{2x}+1)
__device__ __forceinline__ float tanh_(float x){ return 1.0f - 2.0f*rcp_(__expf(2.0f*x) + 1.0f); }

// ABLATION (single variable vs 15.6ms baseline): in-loop barriers drain only
// LDS counters; global stores/loads stay in flight across the barrier.
__device__ __forceinline__ void barrier_lds_(){
    asm volatile("s_waitcnt lgkmcnt(0)" ::: "memory");
    __builtin_amdgcn_s_barrier();
    asm volatile("" ::: "memory");
}

__global__ __launch_bounds__(512, 2)
void decoder_kernel(const float* __restrict__ enc,   // (B,1,N,E)
                    const float* __restrict__ mean,  // (B,FUT,N,O)
                    const float* __restrict__ sv,    // (1,O)
                    const float* __restrict__ h0,    // (2,O)
                    const float* __restrict__ c0,    // (2,H)
                    const float* __restrict__ Wih0,  // (G, E+O)
                    const float* __restrict__ Whh0,  // (G, O)
                    const float* __restrict__ bih0,  // (G)
                    const float* __restrict__ bhh0,  // (G)
                    const float* __restrict__ Whr0,  // (O, H)
                    const float* __restrict__ Wih1,  // (G, O)
                    const float* __restrict__ Whh1,  // (G, O)
                    const float* __restrict__ bih1,  // (G)
                    const float* __restrict__ bhh1,  // (G)
                    const float* __restrict__ Whr1,  // (O, H)
                    float* __restrict__ out)         // (B,FUT,N,O)
{
    const int t = threadIdx.x;   // gate index for both layers
    const int b = blockIdx.x;    // batch chain

    __shared__ float s_last[OO];
    __shared__ float s_h1[OO];
    __shared__ float s_h2[OO];
    __shared__ float s_gates[GG];
    __shared__ float s_hfull[HH];
    __shared__ float s_enc[EE];
    __shared__ float s_nm[OO];

    // ---- per-thread weights in registers ----
    float w_enc[EE];                       // W_ih0[t, 0:64]  (enc part, used once/node)
    float w_loop[OO], w_hh0[OO], w_ih1[OO], w_hh1[OO];
    {
        const float* r = Wih0 + t*(EE+OO);
        #pragma unroll
        for (int e=0;e<EE;e++) w_enc[e] = r[e];
        #pragma unroll
        for (int j=0;j<OO;j++) w_loop[j] = r[EE+j];
        #pragma unroll
        for (int j=0;j<OO;j++) w_hh0[j] = Whh0[t*OO+j];
        #pragma unroll
        for (int j=0;j<OO;j++) w_ih1[j] = Wih1[t*OO+j];
        #pragma unroll
        for (int j=0;j<OO;j++) w_hh1[j] = Whh1[t*OO+j];
    }
    const float bias0 = bih0[t] + bhh0[t];
    const float bias1 = bih1[t] + bhh1[t];

    // projection assignment: output j16 = t>>5, k-chunk kb = (t&31)*4
    const int j16 = t >> 5;
    const int kb  = (t & 31) * 4;
    float wp0[4], wp1[4];
    #pragma unroll
    for (int u=0;u<4;u++){
        wp0[u] = Whr0[j16*HH + kb + u];
        wp1[u] = Whr1[j16*HH + kb + u];
    }

    // cell state lives in the registers of threads 0..127
    float c1 = (t < HH) ? c0[t]      : 0.0f;
    float c2 = (t < HH) ? c0[HH + t] : 0.0f;
    if (t < OO){
        s_last[t] = sv[t];        // last0 = s[0]
        s_h1[t]   = h0[t];        // h_0[0]
        s_h2[t]   = h0[OO + t];   // h_0[1]
    }
    __syncthreads();

    const float* encB  = enc  + (size_t)b * NN * EE;
    const float* meanB = mean + (size_t)b * FF * NN * OO;
    float*       outB  = out  + (size_t)b * FF * NN * OO;

    const bool isTanhGate = ((t >> 7) == 2);   // gates[256:384] are 'g' -> tanh

    for (int n = 0; n < NN; ++n){
        // ---- per-node loads: enc_t and node_mean ----
        if (t < EE){
            s_enc[t] = encB[n*EE + t];
        } else if (t < EE + OO){
            const int j = t - EE;
            float a = 0.0f;
            #pragma unroll
            for (int f=0; f<FF; ++f) a += meanB[(f*NN + n)*OO + j];
            s_nm[j] = a * (1.0f/12.0f);
        }
        __syncthreads();

        // per-node constant part of layer-0 gate t
        float pre0 = bias0;
        #pragma unroll
        for (int e=0;e<EE;e++) pre0 += s_enc[e]*w_enc[e];
        #pragma unroll
        for (int j=0;j<OO;j++) pre0 += s_nm[j]*w_loop[j];

        for (int f=0; f<FF; ++f){
            // ---- layer 0 gates (K=16 + K=16) ----
            float acc = pre0;
            #pragma unroll
            for (int j=0;j<OO;j++) acc += s_last[j]*w_loop[j];
            #pragma unroll
            for (int j=0;j<OO;j++) acc += s_h1[j]*w_hh0[j];
            s_gates[t] = isTanhGate ? tanh_(acc) : sigm_(acc);
            barrier_lds_();                                    // B1

            // ---- layer 0 cell (threads 0..127) ----
            if (t < HH){
                float iv = s_gates[t],      fv = s_gates[HH + t];
                float gv = s_gates[2*HH+t], ov = s_gates[3*HH + t];
                c1 = fv*c1 + iv*gv;
                s_hfull[t] = ov * tanh_(c1);
            }
            barrier_lds_();                                    // B2

            // ---- layer 0 projection: h1_new[j] = sum_k hfull[k]*Whr0[j,k] ----
            {
                float p = s_hfull[kb+0]*wp0[0] + s_hfull[kb+1]*wp0[1]
                        + s_hfull[kb+2]*wp0[2] + s_hfull[kb+3]*wp0[3];
                p += __shfl_down(p, 16, 32);
                p += __shfl_down(p,  8, 32);
                p += __shfl_down(p,  4, 32);
                p += __shfl_down(p,  2, 32);
                p += __shfl_down(p,  1, 32);
                if ((t & 31) == 0) s_h1[j16] = p;
            }
            barrier_lds_();                                    // B3

            // ---- layer 1 gates (K=16 + K=16) ----
            float acc1 = bias1;
            #pragma unroll
            for (int j=0;j<OO;j++) acc1 += s_h1[j]*w_ih1[j];
            #pragma unroll
            for (int j=0;j<OO;j++) acc1 += s_h2[j]*w_hh1[j];
            s_gates[t] = isTanhGate ? tanh_(acc1) : sigm_(acc1);
            barrier_lds_();                                    // B4

            // ---- layer 1 cell ----
            if (t < HH){
                float iv = s_gates[t],      fv = s_gates[HH + t];
                float gv = s_gates[2*HH+t], ov = s_gates[3*HH + t];
                c2 = fv*c2 + iv*gv;
                s_hfull[t] = ov * tanh_(c2);
            }
            barrier_lds_();                                    // B5

            // ---- layer 1 projection + output ----
            {
                float p = s_hfull[kb+0]*wp1[0] + s_hfull[kb+1]*wp1[1]
                        + s_hfull[kb+2]*wp1[2] + s_hfull[kb+3]*wp1[3];
                p += __shfl_down(p, 16, 32);
                p += __shfl_down(p,  8, 32);
                p += __shfl_down(p,  4, 32);
                p += __shfl_down(p,  2, 32);
                p += __shfl_down(p,  1, 32);
                if ((t & 31) == 0){
                    s_h2[j16]   = p;     // new h2
                    s_last[j16] = p;     // new 'last'
                    outB[(f*NN + n)*OO + j16] = p + s_nm[j16];
                }
            }
            barrier_lds_();                                    // B6
        }
    }
}

extern "C" void kernel_launch(void* const* d_in, const int* in_sizes, int n_in,
                              void* d_out, int out_size, void* d_ws, size_t ws_size,
                              hipStream_t stream) {
    const float* enc  = (const float*)d_in[0];
    const float* mean = (const float*)d_in[1];
    const float* sv   = (const float*)d_in[2];
    const float* h0   = (const float*)d_in[3];
    const float* c0   = (const float*)d_in[4];
    const float* Wih0 = (const float*)d_in[5];
    const float* Whh0 = (const float*)d_in[6];
    const float* bih0 = (const float*)d_in[7];
    const float* bhh0 = (const float*)d_in[8];
    const float* Whr0 = (const float*)d_in[9];
    const float* Wih1 = (const float*)d_in[10];
    const float* Whh1 = (const float*)d_in[11];
    const float* bih1 = (const float*)d_in[12];
    const float* bhh1 = (const float*)d_in[13];
    const float* Whr1 = (const float*)d_in[14];
    float* out = (float*)d_out;

    decoder_kernel<<<dim3(BB), dim3(512), 0, stream>>>(
        enc, mean, sv, h0, c0,
        Wih0, Whh0, bih0, bhh0, Whr0,
        Wih1, Whh1, bih1, bhh1, Whr1,
        out);
}